// Round 1
// baseline (830.347 us; speedup 1.0000x reference)
//
#include <hip/hip_runtime.h>

#define NBATCH   16384
#define TSTEPS   50
#define HDIM     64
#define G4       256
#define HOR      50
#define NB       32   // batches per block
#define NW       8    // batches per wave
#define NTHREADS 256

__device__ __forceinline__ float frcp(float x) { return __builtin_amdgcn_rcpf(x); }
__device__ __forceinline__ float sigmoidf(float x) { return frcp(1.f + __expf(-x)); }
__device__ __forceinline__ float tanh_fast(float x) {
  float ax = fabsf(x);
  float e  = __expf(-2.f * ax);
  float r  = (1.f - e) * frcp(1.f + e);
  return copysignf(r, x);
}

__global__ __launch_bounds__(NTHREADS, 2)
void traj_lstm_kernel(const float* __restrict__ hist,   // (B, 50, 2)
                      const float* __restrict__ W_ih,   // (256, 2)
                      const float* __restrict__ W_hh,   // (256, 64)
                      const float* __restrict__ b_ih,   // (256)
                      const float* __restrict__ b_hh,   // (256)
                      const float* __restrict__ W_dec,  // (2, 64)
                      const float* __restrict__ b_dec,  // (2)
                      float* __restrict__ out)          // (B, 50, 2)
{
  __shared__ float Wt[HDIM][G4];        // W_hh transposed: Wt[k][r] = W_hh[r][k]
  __shared__ float hbuf[NB][HDIM + 4];  // padded rows (decoder-read bank spread)
  __shared__ float Wd[2][HDIM];
  __shared__ float xdec[NB][2];

  const int t  = threadIdx.x;
  const int j  = t & 63;    // hidden index owned by this lane
  const int w  = t >> 6;    // wave id (0..3)
  const int lb = w * NW;    // local batch base
  const int gb = blockIdx.x * NB + lb;

  // ---- one-time staging ----
  for (int idx = t; idx < G4 * HDIM; idx += NTHREADS)
    Wt[idx & 63][idx >> 6] = W_hh[idx];
  if (t < 2 * HDIM) Wd[t >> 6][t & 63] = W_dec[t];

  float biasr[4], wi0[4], wi1[4];
  #pragma unroll
  for (int g = 0; g < 4; ++g) {
    int r = j + 64 * g;
    biasr[g] = b_ih[r] + b_hh[r];
    wi0[g]   = W_ih[2 * r];
    wi1[g]   = W_ih[2 * r + 1];
  }
  const float wdec0 = 0.f; (void)wdec0;
  const float bd0 = b_dec[0], bd1 = b_dec[1];

  float c[NW];
  #pragma unroll
  for (int bb = 0; bb < NW; ++bb) {
    c[bb] = 0.f;
    hbuf[lb + bb][j] = 0.f;
  }
  __syncthreads();  // Wt/Wd visible to all waves; loop below is barrier-free

  const float2* __restrict__ histv = (const float2*)hist;

  for (int s = 0; s < TSTEPS + HOR; ++s) {
    // ---- input x for this step ----
    float x0[NW], x1[NW];
    if (s <= TSTEPS) {
      const int ss = (s < TSTEPS) ? s : (TSTEPS - 1);
      #pragma unroll
      for (int bb = 0; bb < NW; ++bb) {
        float2 xv = histv[(size_t)(gb + bb) * TSTEPS + ss];
        x0[bb] = xv.x; x1[bb] = xv.y;
      }
    } else {
      #pragma unroll
      for (int bb = 0; bb < NW; ++bb) {
        x0[bb] = xdec[lb + bb][0];
        x1[bb] = xdec[lb + bb][1];
      }
    }

    // ---- gates = h @ W_hh.T  (8 batches x 4 gate-rows per lane) ----
    float acc[NW][4];
    #pragma unroll
    for (int bb = 0; bb < NW; ++bb) {
      acc[bb][0] = 0.f; acc[bb][1] = 0.f; acc[bb][2] = 0.f; acc[bb][3] = 0.f;
    }

    #pragma unroll 4
    for (int kq = 0; kq < HDIM; kq += 4) {
      float4 h4[NW];
      #pragma unroll
      for (int bb = 0; bb < NW; ++bb)
        h4[bb] = *(const float4*)&hbuf[lb + bb][kq];   // broadcast read
      #pragma unroll
      for (int kk = 0; kk < 4; ++kk) {
        const int k = kq + kk;
        const float w0 = Wt[k][j];
        const float w1 = Wt[k][j + 64];
        const float w2 = Wt[k][j + 128];
        const float w3 = Wt[k][j + 192];
        #pragma unroll
        for (int bb = 0; bb < NW; ++bb) {
          const float hv = (&h4[bb].x)[kk];
          acc[bb][0] = fmaf(hv, w0, acc[bb][0]);
          acc[bb][1] = fmaf(hv, w1, acc[bb][1]);
          acc[bb][2] = fmaf(hv, w2, acc[bb][2]);
          acc[bb][3] = fmaf(hv, w3, acc[bb][3]);
        }
      }
    }

    // ---- elementwise LSTM cell ----
    #pragma unroll
    for (int bb = 0; bb < NW; ++bb) {
      float gi = acc[bb][0] + biasr[0] + x0[bb] * wi0[0] + x1[bb] * wi1[0];
      float gf = acc[bb][1] + biasr[1] + x0[bb] * wi0[1] + x1[bb] * wi1[1];
      float gg = acc[bb][2] + biasr[2] + x0[bb] * wi0[2] + x1[bb] * wi1[2];
      float go = acc[bb][3] + biasr[3] + x0[bb] * wi0[3] + x1[bb] * wi1[3];
      float si = sigmoidf(gi);
      float sf = sigmoidf(gf);
      float tg = tanh_fast(gg);
      float so = sigmoidf(go);
      float cn = fmaf(sf, c[bb], si * tg);
      c[bb] = cn;
      hbuf[lb + bb][j] = so * tanh_fast(cn);   // wave-local, in-order
    }

    // ---- decoder head: dxy = h @ W_dec.T + b_dec (wave-internal) ----
    if (s >= TSTEPS) {
      const int bl = j >> 3;        // batch within wave (0..7)
      const int f  = (j >> 2) & 1;  // output feature
      const int p  = j & 3;         // k-slice
      const float* hr = &hbuf[lb + bl][p * 16];
      const float* wr = &Wd[f][p * 16];
      float part = 0.f;
      #pragma unroll
      for (int e = 0; e < 4; ++e) {
        float4 hv = *(const float4*)&hr[e * 4];
        float4 wv = *(const float4*)&wr[e * 4];
        part += hv.x * wv.x + hv.y * wv.y + hv.z * wv.z + hv.w * wv.w;
      }
      part += __shfl_xor(part, 1);
      part += __shfl_xor(part, 2);
      const float dxy = part + (f ? bd1 : bd0);
      if (p == 0) {
        xdec[lb + bl][f] = dxy;     // feedback for next step (same wave)
        out[(size_t)(gb + bl) * (HOR * 2) + (size_t)(s - TSTEPS) * 2 + f] = dxy;
      }
    }
  }
}

extern "C" void kernel_launch(void* const* d_in, const int* in_sizes, int n_in,
                              void* d_out, int out_size, void* d_ws, size_t ws_size,
                              hipStream_t stream) {
  (void)in_sizes; (void)n_in; (void)ws_size; (void)d_ws; (void)out_size;
  const float* hist  = (const float*)d_in[0];
  const float* W_ih  = (const float*)d_in[1];
  const float* W_hh  = (const float*)d_in[2];
  const float* b_ih  = (const float*)d_in[3];
  const float* b_hh  = (const float*)d_in[4];
  const float* W_dec = (const float*)d_in[5];
  const float* b_dec = (const float*)d_in[6];
  float* out = (float*)d_out;

  dim3 grid(NBATCH / NB);   // 512 blocks
  dim3 block(NTHREADS);
  traj_lstm_kernel<<<grid, block, 0, stream>>>(hist, W_ih, W_hh, b_ih, b_hh,
                                               W_dec, b_dec, out);
}

// Round 2
// 823.520 us; speedup vs baseline: 1.0083x; 1.0083x over previous
//
#include <hip/hip_runtime.h>

#define NBATCH   16384
#define TSTEPS   50
#define HDIM     64
#define HOR      50
#define NB       32   // batches per block
#define NW       8    // batches per wave
#define NTHREADS 256

__device__ __forceinline__ float frcp(float x) { return __builtin_amdgcn_rcpf(x); }
__device__ __forceinline__ float sigmoidf(float x) { return frcp(1.f + __expf(-x)); }
__device__ __forceinline__ float tanh_fast(float x) {
  float ax = fabsf(x);
  float e  = __expf(-2.f * ax);
  float r  = (1.f - e) * frcp(1.f + e);
  return copysignf(r, x);
}

__global__ __launch_bounds__(NTHREADS, 2)
void traj_lstm_kernel(const float* __restrict__ hist,   // (B, 50, 2)
                      const float* __restrict__ W_ih,   // (256, 2)
                      const float* __restrict__ W_hh,   // (256, 64)
                      const float* __restrict__ b_ih,   // (256)
                      const float* __restrict__ b_hh,   // (256)
                      const float* __restrict__ W_dec,  // (2, 64)
                      const float* __restrict__ b_dec,  // (2)
                      float* __restrict__ out)          // (B, 50, 2)
{
  // Wq[k][j] = { W_hh[j][k], W_hh[j+64][k], W_hh[j+128][k], W_hh[j+192][k] }
  // -> one conflict-free ds_read_b128 per k yields all 4 gate weights.
  __shared__ float4 Wq[HDIM][HDIM];     // 64 KB
  __shared__ float hbuf[NB][HDIM + 4];  // padded rows
  __shared__ float Wd[2][HDIM];
  __shared__ float xdec[NB][2];

  const int t  = threadIdx.x;
  const int j  = t & 63;    // hidden index owned by this lane
  const int w  = t >> 6;    // wave id (0..3)
  const int lb = w * NW;    // local batch base
  const int gb = blockIdx.x * NB + lb;

  // ---- one-time staging (gather 4 gate weights -> one b128 write, stride-16B
  //      across lanes => conflict-free; reads are L2-resident 64 KB) ----
  for (int idx = t; idx < HDIM * HDIM; idx += NTHREADS) {
    const int jj = idx & 63;
    const int kk = idx >> 6;
    float4 wv;
    wv.x = W_hh[(jj      ) * HDIM + kk];
    wv.y = W_hh[(jj +  64) * HDIM + kk];
    wv.z = W_hh[(jj + 128) * HDIM + kk];
    wv.w = W_hh[(jj + 192) * HDIM + kk];
    Wq[kk][jj] = wv;
  }
  if (t < 2 * HDIM) Wd[t >> 6][t & 63] = W_dec[t];

  float biasr[4], wi0[4], wi1[4];
  #pragma unroll
  for (int g = 0; g < 4; ++g) {
    int r = j + 64 * g;
    biasr[g] = b_ih[r] + b_hh[r];
    wi0[g]   = W_ih[2 * r];
    wi1[g]   = W_ih[2 * r + 1];
  }
  const float bd0 = b_dec[0], bd1 = b_dec[1];

  float c[NW];
  #pragma unroll
  for (int bb = 0; bb < NW; ++bb) {
    c[bb] = 0.f;
    hbuf[lb + bb][j] = 0.f;
  }
  __syncthreads();  // Wq/Wd visible; loop below is barrier-free (wave-local rows)

  const float2* __restrict__ histv = (const float2*)hist;

  for (int s = 0; s < TSTEPS + HOR; ++s) {
    // ---- input x for this step ----
    float x0[NW], x1[NW];
    if (s <= TSTEPS) {
      const int ss = (s < TSTEPS) ? s : (TSTEPS - 1);
      #pragma unroll
      for (int bb = 0; bb < NW; ++bb) {
        float2 xv = histv[(size_t)(gb + bb) * TSTEPS + ss];
        x0[bb] = xv.x; x1[bb] = xv.y;
      }
    } else {
      #pragma unroll
      for (int bb = 0; bb < NW; ++bb) {
        x0[bb] = xdec[lb + bb][0];
        x1[bb] = xdec[lb + bb][1];
      }
    }

    // ---- gates = h @ W_hh.T  (8 batches x 4 gate-rows per lane) ----
    float acc[NW][4];
    #pragma unroll
    for (int bb = 0; bb < NW; ++bb) {
      acc[bb][0] = 0.f; acc[bb][1] = 0.f; acc[bb][2] = 0.f; acc[bb][3] = 0.f;
    }

    #pragma unroll
    for (int kq = 0; kq < HDIM; kq += 4) {
      float4 h4[NW];
      #pragma unroll
      for (int bb = 0; bb < NW; ++bb)
        h4[bb] = *(const float4*)&hbuf[lb + bb][kq];   // broadcast read
      #pragma unroll
      for (int kk = 0; kk < 4; ++kk) {
        const float4 wv = Wq[kq + kk][j];              // one b128, 4 gate weights
        #pragma unroll
        for (int bb = 0; bb < NW; ++bb) {
          const float hv = (&h4[bb].x)[kk];
          acc[bb][0] = fmaf(hv, wv.x, acc[bb][0]);
          acc[bb][1] = fmaf(hv, wv.y, acc[bb][1]);
          acc[bb][2] = fmaf(hv, wv.z, acc[bb][2]);
          acc[bb][3] = fmaf(hv, wv.w, acc[bb][3]);
        }
      }
    }

    // ---- elementwise LSTM cell ----
    #pragma unroll
    for (int bb = 0; bb < NW; ++bb) {
      float gi = acc[bb][0] + biasr[0] + x0[bb] * wi0[0] + x1[bb] * wi1[0];
      float gf = acc[bb][1] + biasr[1] + x0[bb] * wi0[1] + x1[bb] * wi1[1];
      float gg = acc[bb][2] + biasr[2] + x0[bb] * wi0[2] + x1[bb] * wi1[2];
      float go = acc[bb][3] + biasr[3] + x0[bb] * wi0[3] + x1[bb] * wi1[3];
      float si = sigmoidf(gi);
      float sf = sigmoidf(gf);
      float tg = tanh_fast(gg);
      float so = sigmoidf(go);
      float cn = fmaf(sf, c[bb], si * tg);
      c[bb] = cn;
      hbuf[lb + bb][j] = so * tanh_fast(cn);   // wave-local, in-order
    }

    // ---- decoder head: dxy = h @ W_dec.T + b_dec (wave-internal) ----
    if (s >= TSTEPS) {
      const int bl = j >> 3;        // batch within wave (0..7)
      const int f  = (j >> 2) & 1;  // output feature
      const int p  = j & 3;         // k-slice
      const float* hr = &hbuf[lb + bl][p * 16];
      const float* wr = &Wd[f][p * 16];
      float part = 0.f;
      #pragma unroll
      for (int e = 0; e < 4; ++e) {
        float4 hv = *(const float4*)&hr[e * 4];
        float4 wv = *(const float4*)&wr[e * 4];
        part += hv.x * wv.x + hv.y * wv.y + hv.z * wv.z + hv.w * wv.w;
      }
      part += __shfl_xor(part, 1);
      part += __shfl_xor(part, 2);
      const float dxy = part + (f ? bd1 : bd0);
      if (p == 0) {
        xdec[lb + bl][f] = dxy;     // feedback for next step (same wave)
        out[(size_t)(gb + bl) * (HOR * 2) + (size_t)(s - TSTEPS) * 2 + f] = dxy;
      }
    }
  }
}

extern "C" void kernel_launch(void* const* d_in, const int* in_sizes, int n_in,
                              void* d_out, int out_size, void* d_ws, size_t ws_size,
                              hipStream_t stream) {
  (void)in_sizes; (void)n_in; (void)ws_size; (void)d_ws; (void)out_size;
  const float* hist  = (const float*)d_in[0];
  const float* W_ih  = (const float*)d_in[1];
  const float* W_hh  = (const float*)d_in[2];
  const float* b_ih  = (const float*)d_in[3];
  const float* b_hh  = (const float*)d_in[4];
  const float* W_dec = (const float*)d_in[5];
  const float* b_dec = (const float*)d_in[6];
  float* out = (float*)d_out;

  dim3 grid(NBATCH / NB);   // 512 blocks
  dim3 block(NTHREADS);
  traj_lstm_kernel<<<grid, block, 0, stream>>>(hist, W_ih, W_hh, b_ih, b_hh,
                                               W_dec, b_dec, out);
}